// Round 10
// baseline (1693.126 us; speedup 1.0000x reference)
//
#include <hip/hip_runtime.h>
#include <math.h>

#define NN 50000
#define TT 9
#define FD 128
#define HD 128

using short8 = __attribute__((ext_vector_type(8))) short;
using half8  = __attribute__((ext_vector_type(8))) _Float16;
using f32x4  = __attribute__((ext_vector_type(4))) float;
using f32x2  = __attribute__((ext_vector_type(2))) float;
using half2v = __attribute__((ext_vector_type(2))) _Float16;
typedef unsigned short ushort_t;

__device__ inline float fast_sigmoid(float x) {
  x = fminf(fmaxf(x, -30.f), 30.f);
  return 1.f / (1.f + __expf(-x));
}
__device__ inline float fast_tanh(float x) {
  x = fminf(fmaxf(x, -15.f), 15.f);
  float e = __expf(2.f * x);
  return (e - 1.f) / (e + 1.f);
}

// ---------------------------------------------------------------------------
// CSR build
// ---------------------------------------------------------------------------
__global__ void k_detect(const unsigned int* __restrict__ e32, int nchk,
                         int* __restrict__ stride_out) {
  __shared__ unsigned int red[256];
  unsigned int acc = 0;
  for (int i = threadIdx.x; i < nchk; i += 256) acc |= e32[2 * i + 1];
  red[threadIdx.x] = acc;
  __syncthreads();
  for (int s = 128; s > 0; s >>= 1) {
    if ((int)threadIdx.x < s) red[threadIdx.x] |= red[threadIdx.x + s];
    __syncthreads();
  }
  if (threadIdx.x == 0) stride_out[0] = (red[0] == 0u) ? 2 : 1;
}

__global__ void k_count(const unsigned int* __restrict__ e32, int E,
                        const int* __restrict__ stridep, int* __restrict__ cnt) {
  int e = blockIdx.x * 256 + threadIdx.x;
  if (e >= E) return;
  int st = stridep[0];
  int d = (int)e32[(size_t)(E + e) * st];
  atomicAdd(&cnt[d], 1);
}

__global__ void k_dinv(const int* __restrict__ cnt, float* __restrict__ dinv, int N) {
  int n = blockIdx.x * 256 + threadIdx.x;
  if (n < N) dinv[n] = rsqrtf((float)(cnt[n] + 1));
}

__global__ void k_scan(const int* __restrict__ cnt, int* __restrict__ rowp, int N) {
  __shared__ int buf[1024];
  __shared__ int carry_s;
  if (threadIdx.x == 0) carry_s = 0;
  __syncthreads();
  for (int base = 0; base < N; base += 1024) {
    int i = base + threadIdx.x;
    int v = (i < N) ? cnt[i] : 0;
    buf[threadIdx.x] = v;
    __syncthreads();
    for (int off = 1; off < 1024; off <<= 1) {
      int t = ((int)threadIdx.x >= off) ? buf[threadIdx.x - off] : 0;
      __syncthreads();
      buf[threadIdx.x] += t;
      __syncthreads();
    }
    int incl = buf[threadIdx.x];
    int carry = carry_s;
    if (i < N) rowp[i] = carry + incl - v;
    __syncthreads();
    if (threadIdx.x == 1023) carry_s = carry + incl;
    __syncthreads();
  }
  if (threadIdx.x == 0) rowp[N] = carry_s;
}

__global__ void k_scatter(const unsigned int* __restrict__ e32, int E,
                          const int* __restrict__ stridep, const int* __restrict__ rowp,
                          int* __restrict__ fill, int* __restrict__ col) {
  int e = blockIdx.x * 256 + threadIdx.x;
  if (e >= E) return;
  int st = stridep[0];
  int s = (int)e32[(size_t)e * st];
  int d = (int)e32[(size_t)(E + e) * st];
  int pos = rowp[d] + atomicAdd(&fill[d], 1);
  col[pos] = s;
}

// ---------------------------------------------------------------------------
// k_prep: xs16[t][n][128] = fp16( x_seq[t][n][d] * dinv[n] )
// ---------------------------------------------------------------------------
__global__ __launch_bounds__(256) void k_prep(const float* __restrict__ x,
                                              const float* __restrict__ dinv,
                                              _Float16* __restrict__ xs) {
  int lane = threadIdx.x & 63;
  int n = blockIdx.x * 4 + (threadIdx.x >> 6);
  int t = blockIdx.y;
  float dn = dinv[n];
  f32x2 v = __builtin_nontemporal_load(
      (const f32x2*)(x + ((size_t)t * NN + n) * 128 + lane * 2));
  half2v r;
  r.x = (_Float16)(v.x * dn);
  r.y = (_Float16)(v.y * dn);
  *(half2v*)(xs + ((size_t)t * NN + n) * 128 + lane * 2) = r;
}

// ---------------------------------------------------------------------------
// Weight packs (k-chunked [koct][row][8], f16 hi/lo split: w = hi + lo exact
// to ~2^-22; activation operand carries the only quantization).
// ---------------------------------------------------------------------------
__global__ void k_packw(const float* __restrict__ Wih, const float* __restrict__ Whh,
                        const float* __restrict__ bih, const float* __restrict__ bhh,
                        _Float16* __restrict__ Wh_, _Float16* __restrict__ Wl_,
                        float* __restrict__ bsum) {
  int r = blockIdx.x;   // 0..511 original gate-row
  int k = threadIdx.x;  // 0..255
  int ri = (r & 127) * 4 + (r >> 7);
  float v = (k < 128) ? Wih[(size_t)r * 128 + k] : Whh[(size_t)r * 128 + (k - 128)];
  _Float16 hi = (_Float16)v;
  _Float16 lo = (_Float16)(v - (float)hi);
  size_t o = ((size_t)(k >> 3) * 512 + ri) * 8 + (k & 7);
  Wh_[o] = hi;
  Wl_[o] = lo;
  if (k == 0) bsum[ri] = bih[r] + bhh[r];
}

__global__ void k_packg(const float* __restrict__ Wg, _Float16* __restrict__ Gh_,
                        _Float16* __restrict__ Gl_) {
  int h = blockIdx.x, k = threadIdx.x;  // 128 x 128
  float v = Wg[(size_t)k * 128 + h];
  _Float16 hi = (_Float16)v;
  _Float16 lo = (_Float16)(v - (float)hi);
  size_t o = ((size_t)(k >> 3) * 128 + h) * 8 + (k & 7);
  Gh_[o] = hi;
  Gl_[o] = lo;
}

// ---------------------------------------------------------------------------
// k_agg: grid (N/4, 9) — per-t so the gather working set is 12.8MB. Wave =
// node, full 128-dim fp16 row gather, 8-edge unroll. fp32 accumulate; fp16
// output in k-chunked [koct][t][n][8] layout.
// ---------------------------------------------------------------------------
__global__ __launch_bounds__(256) void k_agg(const _Float16* __restrict__ xs,
                                             const float* __restrict__ dinv,
                                             const int* __restrict__ rowp,
                                             const int* __restrict__ col,
                                             _Float16* __restrict__ agg16) {
  __shared__ unsigned int pk[4][132];
  int lane = threadIdx.x & 63;
  int wv = threadIdx.x >> 6;
  int n = blockIdx.x * 4 + wv;
  int t = blockIdx.y;
  const _Float16* xb = xs + (size_t)t * NN * 128;
  float dn = dinv[n];
  half2v sv = *(const half2v*)(xb + (size_t)n * 128 + lane * 2);
  float ax = (float)sv.x, ay = (float)sv.y;  // self-loop (xs pre-scaled by dinv)
  int beg = rowp[n], end = rowp[n + 1];
  for (int base = beg; base < end; base += 64) {
    int m = end - base;
    if (m > 64) m = 64;
    int sl = (lane < m) ? col[base + lane] : 0;
    int j = 0;
    for (; j + 8 <= m; j += 8) {
      int s[8];
#pragma unroll
      for (int u = 0; u < 8; ++u) s[u] = __shfl(sl, j + u);
      half2v g[8];
#pragma unroll
      for (int u = 0; u < 8; ++u)
        g[u] = *(const half2v*)(xb + (size_t)s[u] * 128 + lane * 2);
#pragma unroll
      for (int u = 0; u < 8; ++u) {
        ax += (float)g[u].x;
        ay += (float)g[u].y;
      }
    }
    for (; j < m; ++j) {
      int s = __shfl(sl, j);
      half2v g = *(const half2v*)(xb + (size_t)s * 128 + lane * 2);
      ax += (float)g.x;
      ay += (float)g.y;
    }
  }
  half2v r;
  r.x = (_Float16)(ax * dn);
  r.y = (_Float16)(ay * dn);
  union { half2v h; unsigned int u; } cv;
  cv.h = r;
  pk[wv][lane] = cv.u;
  __syncthreads();
  int tid = threadIdx.x;
  if (tid < 64) {
    int g = tid & 3, c = tid >> 2;
    uint4 u4;
    u4.x = pk[g][c * 4 + 0];
    u4.y = pk[g][c * 4 + 1];
    u4.z = pk[g][c * 4 + 2];
    u4.w = pk[g][c * 4 + 3];
    int n2 = blockIdx.x * 4 + g;
    *(uint4*)(agg16 + ((size_t)(c * 9 + t) * NN + n2) * 8) = u4;
  }
}

// ---------------------------------------------------------------------------
// k_fused: GCN GEMM + full T=9 LSTM + out-projection. 512 thr x 96 nodes.
// Activations f16; weights split-f16 hi/lo -> 2 MFMAs per product.
// agg16 reads are NONTEMPORAL (read-once; keep L2 for the weight set).
// LDS 55KB -> 2 blocks/CU; BN=96 halves weight request volume vs BN=48.
// ---------------------------------------------------------------------------
#define BN 96
#define NCT 6
#define LST 136  // LDS row stride in f16 elems (272B)
__global__ __launch_bounds__(512, 2) void k_fused(
    const _Float16* __restrict__ agg16, const _Float16* __restrict__ Gh_,
    const _Float16* __restrict__ Gl_, const float* __restrict__ bg,
    const _Float16* __restrict__ Wh_, const _Float16* __restrict__ Wl_,
    const float* __restrict__ bsum, const float* __restrict__ Wfc,
    const float* __restrict__ bfc, float* __restrict__ out) {
  __shared__ _Float16 ldsE[BN * LST];
  __shared__ _Float16 ldsH[BN * LST];
  __shared__ float obuf[8][BN];
  int tid = threadIdx.x;
  int w = tid >> 6, lane = tid & 63, q = lane >> 4, cl = lane & 15;
  int n0 = blockIdx.x * BN;
  float cst[4][NCT] = {};
  float bfv = bfc[0];
#pragma unroll 1
  for (int t = 0; t < TT; ++t) {
    // ---- Phase E: emb^T = Wgt @ agg^T (A split-f16, B f16: 2 MFMA) ----
    {
      f32x4 acce[NCT] = {};
#pragma unroll 2
      for (int ks = 0; ks < 4; ++ks) {
        int chunk = ks * 4 + q;
        size_t wo = ((size_t)chunk * 128 + w * 16 + cl) * 8;
        half8 gah = *(const half8*)(Gh_ + wo);
        half8 gal = *(const half8*)(Gl_ + wo);
#pragma unroll
        for (int ct = 0; ct < NCT; ++ct) {
          int node = n0 + ct * 16 + cl;
          half8 b = {0, 0, 0, 0, 0, 0, 0, 0};
          if (node < NN)
            b = __builtin_nontemporal_load(
                (const half8*)(agg16 + ((size_t)(chunk * 9 + t) * NN + node) * 8));
          acce[ct] = __builtin_amdgcn_mfma_f32_16x16x32_f16(gah, b, acce[ct], 0, 0, 0);
          acce[ct] = __builtin_amdgcn_mfma_f32_16x16x32_f16(gal, b, acce[ct], 0, 0, 0);
        }
      }
#pragma unroll
      for (int ct = 0; ct < NCT; ++ct) {
#pragma unroll
        for (int j = 0; j < 4; ++j) {
          int hid = w * 16 + q * 4 + j;
          float v = acce[ct][j] + bg[hid];
          v = v > 0.f ? v : 0.f;
          ldsE[(ct * 16 + cl) * LST + hid] = (_Float16)v;
        }
      }
    }
    __syncthreads();  // BAR1: ldsE(t) ready
    // ---- Phase G: gates^T = Wpk @ [emb|h]^T (A split-f16, B f16) ----
    f32x4 acc[4][NCT] = {};
    int ksmax = (t == 0) ? 4 : 8;
#pragma unroll 2
    for (int ks = 0; ks < ksmax; ++ks) {
      int chunk = ks * 4 + q;
      const _Float16* Bp = (ks < 4) ? ldsE : ldsH;
      int kk = (ks & 3) * 32 + q * 8;
      half8 bb[NCT];
#pragma unroll
      for (int ct = 0; ct < NCT; ++ct)
        bb[ct] = *(const half8*)(Bp + (ct * 16 + cl) * LST + kk);
#pragma unroll
      for (int rt = 0; rt < 4; ++rt) {
        size_t ao = ((size_t)chunk * 512 + w * 64 + rt * 16 + cl) * 8;
        half8 ah = *(const half8*)(Wh_ + ao);
        half8 al = *(const half8*)(Wl_ + ao);
#pragma unroll
        for (int ct = 0; ct < NCT; ++ct) {
          acc[rt][ct] = __builtin_amdgcn_mfma_f32_16x16x32_f16(ah, bb[ct], acc[rt][ct], 0, 0, 0);
          acc[rt][ct] = __builtin_amdgcn_mfma_f32_16x16x32_f16(al, bb[ct], acc[rt][ct], 0, 0, 0);
        }
      }
    }
    __syncthreads();  // BAR2: all ldsE/ldsH reads done before h(t) writes
    // ---- Epilogue ----
    float op[NCT];
#pragma unroll
    for (int ct = 0; ct < NCT; ++ct) op[ct] = 0.f;
#pragma unroll
    for (int rt = 0; rt < 4; ++rt) {
      int jl = w * 16 + rt * 4 + q;
      float4 bs = *(const float4*)(bsum + jl * 4);
      float wf = Wfc[jl];
#pragma unroll
      for (int ct = 0; ct < NCT; ++ct) {
        float gi = acc[rt][ct][0] + bs.x;
        float gf = acc[rt][ct][1] + bs.y;
        float gg = acc[rt][ct][2] + bs.z;
        float go = acc[rt][ct][3] + bs.w;
        float ig = fast_sigmoid(gi), fg = fast_sigmoid(gf), og = fast_sigmoid(go);
        float gt = fast_tanh(gg);
        float cn = fg * cst[rt][ct] + ig * gt;
        cst[rt][ct] = cn;
        float hn = og * fast_tanh(cn);
        op[ct] += hn * wf;
        ldsH[(ct * 16 + cl) * LST + jl] = (_Float16)hn;
      }
    }
#pragma unroll
    for (int ct = 0; ct < NCT; ++ct) {
      op[ct] += __shfl_xor(op[ct], 16);
      op[ct] += __shfl_xor(op[ct], 32);
    }
    if (q == 0) {
#pragma unroll
      for (int ct = 0; ct < NCT; ++ct) obuf[w][ct * 16 + cl] = op[ct];
    }
    __syncthreads();  // BAR3: h(t) + obuf visible
    if (tid < BN) {
      int node = n0 + tid;
      if (node < NN) {
        float v = bfv;
#pragma unroll
        for (int ww = 0; ww < 8; ++ww) v += obuf[ww][tid];
        out[(size_t)node * TT + t] = v;
      }
    }
  }
}

// ---------------------------------------------------------------------------
static inline size_t alignup(size_t x) { return (x + 511) & ~(size_t)511; }

extern "C" void kernel_launch(void* const* d_in, const int* in_sizes, int n_in,
                              void* d_out, int out_size, void* d_ws, size_t ws_size,
                              hipStream_t stream) {
  const float* x_seq = (const float*)d_in[0];
  const unsigned int* e32 = (const unsigned int*)d_in[1];
  const float* W_gcn = (const float*)d_in[2];
  const float* b_gcn = (const float*)d_in[3];
  const float* W_ih = (const float*)d_in[4];
  const float* W_hh = (const float*)d_in[5];
  const float* b_ih = (const float*)d_in[6];
  const float* b_hh = (const float*)d_in[7];
  const float* W_fc = (const float*)d_in[8];
  const float* b_fc = (const float*)d_in[9];
  float* out = (float*)d_out;

  const int N = NN;
  const int E = in_sizes[1] / 2;

  char* p = (char*)d_ws;
  int* stridep = (int*)p;                    p += 512;
  int* cnt = (int*)p;                        p += alignup((size_t)N * 4);
  int* rowp = (int*)p;                       p += alignup((size_t)(N + 1) * 4);
  int* col = (int*)p;                        p += alignup((size_t)E * 4);
  float* dinv = (float*)p;                   p += alignup((size_t)N * 4);
  _Float16* xs16 = (_Float16*)p;             p += alignup((size_t)9 * N * 128 * 2);
  _Float16* agg16 = (_Float16*)p;            p += alignup((size_t)16 * 9 * N * 8 * 2);
  _Float16* wpkh = (_Float16*)p;             p += alignup((size_t)32 * 512 * 8 * 2);
  _Float16* wpkl = (_Float16*)p;             p += alignup((size_t)32 * 512 * 8 * 2);
  _Float16* wgth = (_Float16*)p;             p += alignup((size_t)16 * 128 * 8 * 2);
  _Float16* wgtl = (_Float16*)p;             p += alignup((size_t)16 * 128 * 8 * 2);
  float* bsum = (float*)p;                   p += alignup((size_t)512 * 4);

  hipMemsetAsync(cnt, 0, (size_t)N * 4, stream);

  int nchk = E < 8192 ? E : 8192;
  k_detect<<<1, 256, 0, stream>>>(e32, nchk, stridep);
  k_count<<<(E + 255) / 256, 256, 0, stream>>>(e32, E, stridep, cnt);
  k_dinv<<<(N + 255) / 256, 256, 0, stream>>>(cnt, dinv, N);
  k_scan<<<1, 1024, 0, stream>>>(cnt, rowp, N);
  hipMemsetAsync(cnt, 0, (size_t)N * 4, stream);  // reuse as fill
  k_scatter<<<(E + 255) / 256, 256, 0, stream>>>(e32, E, stridep, rowp, cnt, col);
  k_prep<<<dim3(N / 4, 9), 256, 0, stream>>>(x_seq, dinv, xs16);
  k_packw<<<512, 256, 0, stream>>>(W_ih, W_hh, b_ih, b_hh, wpkh, wpkl, bsum);
  k_packg<<<128, 128, 0, stream>>>(W_gcn, wgth, wgtl);

  k_agg<<<dim3(N / 4, 9), 256, 0, stream>>>(xs16, dinv, rowp, col, agg16);
  k_fused<<<(N + BN - 1) / BN, 512, 0, stream>>>(agg16, wgth, wgtl, b_gcn,
                                                 wpkh, wpkl, bsum, W_fc, b_fc, out);
}

// Round 11
// 1660.698 us; speedup vs baseline: 1.0195x; 1.0195x over previous
//
#include <hip/hip_runtime.h>
#include <math.h>

#define NN 50000
#define TT 9
#define FD 128
#define HD 128

using short8 = __attribute__((ext_vector_type(8))) short;
using half8  = __attribute__((ext_vector_type(8))) _Float16;
using f32x4  = __attribute__((ext_vector_type(4))) float;
using f32x2  = __attribute__((ext_vector_type(2))) float;
using half2v = __attribute__((ext_vector_type(2))) _Float16;
typedef unsigned short ushort_t;

__device__ inline float fast_sigmoid(float x) {
  x = fminf(fmaxf(x, -30.f), 30.f);
  return 1.f / (1.f + __expf(-x));
}
__device__ inline float fast_tanh(float x) {
  x = fminf(fmaxf(x, -15.f), 15.f);
  float e = __expf(2.f * x);
  return (e - 1.f) / (e + 1.f);
}

// ---------------------------------------------------------------------------
// CSR build
// ---------------------------------------------------------------------------
__global__ void k_detect(const unsigned int* __restrict__ e32, int nchk,
                         int* __restrict__ stride_out) {
  __shared__ unsigned int red[256];
  unsigned int acc = 0;
  for (int i = threadIdx.x; i < nchk; i += 256) acc |= e32[2 * i + 1];
  red[threadIdx.x] = acc;
  __syncthreads();
  for (int s = 128; s > 0; s >>= 1) {
    if ((int)threadIdx.x < s) red[threadIdx.x] |= red[threadIdx.x + s];
    __syncthreads();
  }
  if (threadIdx.x == 0) stride_out[0] = (red[0] == 0u) ? 2 : 1;
}

__global__ void k_count(const unsigned int* __restrict__ e32, int E,
                        const int* __restrict__ stridep, int* __restrict__ cnt) {
  int e = blockIdx.x * 256 + threadIdx.x;
  if (e >= E) return;
  int st = stridep[0];
  int d = (int)e32[(size_t)(E + e) * st];
  atomicAdd(&cnt[d], 1);
}

__global__ void k_dinv(const int* __restrict__ cnt, float* __restrict__ dinv, int N) {
  int n = blockIdx.x * 256 + threadIdx.x;
  if (n < N) dinv[n] = rsqrtf((float)(cnt[n] + 1));
}

__global__ void k_scan(const int* __restrict__ cnt, int* __restrict__ rowp, int N) {
  __shared__ int buf[1024];
  __shared__ int carry_s;
  if (threadIdx.x == 0) carry_s = 0;
  __syncthreads();
  for (int base = 0; base < N; base += 1024) {
    int i = base + threadIdx.x;
    int v = (i < N) ? cnt[i] : 0;
    buf[threadIdx.x] = v;
    __syncthreads();
    for (int off = 1; off < 1024; off <<= 1) {
      int t = ((int)threadIdx.x >= off) ? buf[threadIdx.x - off] : 0;
      __syncthreads();
      buf[threadIdx.x] += t;
      __syncthreads();
    }
    int incl = buf[threadIdx.x];
    int carry = carry_s;
    if (i < N) rowp[i] = carry + incl - v;
    __syncthreads();
    if (threadIdx.x == 1023) carry_s = carry + incl;
    __syncthreads();
  }
  if (threadIdx.x == 0) rowp[N] = carry_s;
}

__global__ void k_scatter(const unsigned int* __restrict__ e32, int E,
                          const int* __restrict__ stridep, const int* __restrict__ rowp,
                          int* __restrict__ fill, int* __restrict__ col) {
  int e = blockIdx.x * 256 + threadIdx.x;
  if (e >= E) return;
  int st = stridep[0];
  int s = (int)e32[(size_t)e * st];
  int d = (int)e32[(size_t)(E + e) * st];
  int pos = rowp[d] + atomicAdd(&fill[d], 1);
  col[pos] = s;
}

// ---------------------------------------------------------------------------
// k_prep: xs16[t][n][128] = fp16( x_seq[t][n][d] * dinv[n] )
// ---------------------------------------------------------------------------
__global__ __launch_bounds__(256) void k_prep(const float* __restrict__ x,
                                              const float* __restrict__ dinv,
                                              _Float16* __restrict__ xs) {
  int lane = threadIdx.x & 63;
  int n = blockIdx.x * 4 + (threadIdx.x >> 6);
  int t = blockIdx.y;
  float dn = dinv[n];
  f32x2 v = __builtin_nontemporal_load(
      (const f32x2*)(x + ((size_t)t * NN + n) * 128 + lane * 2));
  half2v r;
  r.x = (_Float16)(v.x * dn);
  r.y = (_Float16)(v.y * dn);
  *(half2v*)(xs + ((size_t)t * NN + n) * 128 + lane * 2) = r;
}

// ---------------------------------------------------------------------------
// Weight packs (k-chunked [koct][row][8], f16 hi/lo split: w = hi + lo exact
// to ~2^-22; activation operand carries the only quantization).
// ---------------------------------------------------------------------------
__global__ void k_packw(const float* __restrict__ Wih, const float* __restrict__ Whh,
                        const float* __restrict__ bih, const float* __restrict__ bhh,
                        _Float16* __restrict__ Wh_, _Float16* __restrict__ Wl_,
                        float* __restrict__ bsum) {
  int r = blockIdx.x;   // 0..511 original gate-row
  int k = threadIdx.x;  // 0..255
  int ri = (r & 127) * 4 + (r >> 7);
  float v = (k < 128) ? Wih[(size_t)r * 128 + k] : Whh[(size_t)r * 128 + (k - 128)];
  _Float16 hi = (_Float16)v;
  _Float16 lo = (_Float16)(v - (float)hi);
  size_t o = ((size_t)(k >> 3) * 512 + ri) * 8 + (k & 7);
  Wh_[o] = hi;
  Wl_[o] = lo;
  if (k == 0) bsum[ri] = bih[r] + bhh[r];
}

__global__ void k_packg(const float* __restrict__ Wg, _Float16* __restrict__ Gh_,
                        _Float16* __restrict__ Gl_) {
  int h = blockIdx.x, k = threadIdx.x;  // 128 x 128
  float v = Wg[(size_t)k * 128 + h];
  _Float16 hi = (_Float16)v;
  _Float16 lo = (_Float16)(v - (float)hi);
  size_t o = ((size_t)(k >> 3) * 128 + h) * 8 + (k & 7);
  Gh_[o] = hi;
  Gl_[o] = lo;
}

// ---------------------------------------------------------------------------
// k_agg: grid (N/4, 9) — per-t so the gather working set is 12.8MB. Wave =
// node, full 128-dim fp16 row gather, 8-edge unroll. fp32 accumulate; fp16
// output in k-chunked [koct][t][n][8] layout.
// ---------------------------------------------------------------------------
__global__ __launch_bounds__(256) void k_agg(const _Float16* __restrict__ xs,
                                             const float* __restrict__ dinv,
                                             const int* __restrict__ rowp,
                                             const int* __restrict__ col,
                                             _Float16* __restrict__ agg16) {
  __shared__ unsigned int pk[4][132];
  int lane = threadIdx.x & 63;
  int wv = threadIdx.x >> 6;
  int n = blockIdx.x * 4 + wv;
  int t = blockIdx.y;
  const _Float16* xb = xs + (size_t)t * NN * 128;
  float dn = dinv[n];
  half2v sv = *(const half2v*)(xb + (size_t)n * 128 + lane * 2);
  float ax = (float)sv.x, ay = (float)sv.y;  // self-loop (xs pre-scaled by dinv)
  int beg = rowp[n], end = rowp[n + 1];
  for (int base = beg; base < end; base += 64) {
    int m = end - base;
    if (m > 64) m = 64;
    int sl = (lane < m) ? col[base + lane] : 0;
    int j = 0;
    for (; j + 8 <= m; j += 8) {
      int s[8];
#pragma unroll
      for (int u = 0; u < 8; ++u) s[u] = __shfl(sl, j + u);
      half2v g[8];
#pragma unroll
      for (int u = 0; u < 8; ++u)
        g[u] = *(const half2v*)(xb + (size_t)s[u] * 128 + lane * 2);
#pragma unroll
      for (int u = 0; u < 8; ++u) {
        ax += (float)g[u].x;
        ay += (float)g[u].y;
      }
    }
    for (; j < m; ++j) {
      int s = __shfl(sl, j);
      half2v g = *(const half2v*)(xb + (size_t)s * 128 + lane * 2);
      ax += (float)g.x;
      ay += (float)g.y;
    }
  }
  half2v r;
  r.x = (_Float16)(ax * dn);
  r.y = (_Float16)(ay * dn);
  union { half2v h; unsigned int u; } cv;
  cv.h = r;
  pk[wv][lane] = cv.u;
  __syncthreads();
  int tid = threadIdx.x;
  if (tid < 64) {
    int g = tid & 3, c = tid >> 2;
    uint4 u4;
    u4.x = pk[g][c * 4 + 0];
    u4.y = pk[g][c * 4 + 1];
    u4.z = pk[g][c * 4 + 2];
    u4.w = pk[g][c * 4 + 3];
    int n2 = blockIdx.x * 4 + g;
    *(uint4*)(agg16 + ((size_t)(c * 9 + t) * NN + n2) * 8) = u4;
  }
}

// ---------------------------------------------------------------------------
// k_fused: GCN GEMM + full T=9 LSTM + out-projection. 512 thr x 48 nodes.
// Activations f16; weights split-f16 hi/lo -> 2 MFMAs per product.
// agg16 reads NONTEMPORAL (read-once stream; keep L2 for weight set).
// BN=48: VGPR 64, LDS 27KB -> 4+ blocks/CU (the r7/r9-proven occupancy shape).
// ---------------------------------------------------------------------------
#define BN 48
#define NCT 3
#define LST 136  // LDS row stride in f16 elems (272B)
__global__ __launch_bounds__(512, 4) void k_fused(
    const _Float16* __restrict__ agg16, const _Float16* __restrict__ Gh_,
    const _Float16* __restrict__ Gl_, const float* __restrict__ bg,
    const _Float16* __restrict__ Wh_, const _Float16* __restrict__ Wl_,
    const float* __restrict__ bsum, const float* __restrict__ Wfc,
    const float* __restrict__ bfc, float* __restrict__ out) {
  __shared__ _Float16 ldsE[BN * LST];
  __shared__ _Float16 ldsH[BN * LST];
  __shared__ float obuf[8][BN];
  int tid = threadIdx.x;
  int w = tid >> 6, lane = tid & 63, q = lane >> 4, cl = lane & 15;
  int n0 = blockIdx.x * BN;
  float cst[4][NCT] = {};
  float bfv = bfc[0];
#pragma unroll 1
  for (int t = 0; t < TT; ++t) {
    // ---- Phase E: emb^T = Wgt @ agg^T (A split-f16, B f16: 2 MFMA) ----
    {
      f32x4 acce[NCT] = {};
#pragma unroll 2
      for (int ks = 0; ks < 4; ++ks) {
        int chunk = ks * 4 + q;
        size_t wo = ((size_t)chunk * 128 + w * 16 + cl) * 8;
        half8 gah = *(const half8*)(Gh_ + wo);
        half8 gal = *(const half8*)(Gl_ + wo);
#pragma unroll
        for (int ct = 0; ct < NCT; ++ct) {
          int node = n0 + ct * 16 + cl;
          half8 b = {0, 0, 0, 0, 0, 0, 0, 0};
          if (node < NN)
            b = __builtin_nontemporal_load(
                (const half8*)(agg16 + ((size_t)(chunk * 9 + t) * NN + node) * 8));
          acce[ct] = __builtin_amdgcn_mfma_f32_16x16x32_f16(gah, b, acce[ct], 0, 0, 0);
          acce[ct] = __builtin_amdgcn_mfma_f32_16x16x32_f16(gal, b, acce[ct], 0, 0, 0);
        }
      }
#pragma unroll
      for (int ct = 0; ct < NCT; ++ct) {
#pragma unroll
        for (int j = 0; j < 4; ++j) {
          int hid = w * 16 + q * 4 + j;
          float v = acce[ct][j] + bg[hid];
          v = v > 0.f ? v : 0.f;
          ldsE[(ct * 16 + cl) * LST + hid] = (_Float16)v;
        }
      }
    }
    __syncthreads();  // BAR1: ldsE(t) ready
    // ---- Phase G: gates^T = Wpk @ [emb|h]^T (A split-f16, B f16) ----
    f32x4 acc[4][NCT] = {};
    int ksmax = (t == 0) ? 4 : 8;
#pragma unroll 2
    for (int ks = 0; ks < ksmax; ++ks) {
      int chunk = ks * 4 + q;
      const _Float16* Bp = (ks < 4) ? ldsE : ldsH;
      int kk = (ks & 3) * 32 + q * 8;
      half8 bb[NCT];
#pragma unroll
      for (int ct = 0; ct < NCT; ++ct)
        bb[ct] = *(const half8*)(Bp + (ct * 16 + cl) * LST + kk);
#pragma unroll
      for (int rt = 0; rt < 4; ++rt) {
        size_t ao = ((size_t)chunk * 512 + w * 64 + rt * 16 + cl) * 8;
        half8 ah = *(const half8*)(Wh_ + ao);
        half8 al = *(const half8*)(Wl_ + ao);
#pragma unroll
        for (int ct = 0; ct < NCT; ++ct) {
          acc[rt][ct] = __builtin_amdgcn_mfma_f32_16x16x32_f16(ah, bb[ct], acc[rt][ct], 0, 0, 0);
          acc[rt][ct] = __builtin_amdgcn_mfma_f32_16x16x32_f16(al, bb[ct], acc[rt][ct], 0, 0, 0);
        }
      }
    }
    __syncthreads();  // BAR2: all ldsE/ldsH reads done before h(t) writes
    // ---- Epilogue ----
    float op[NCT];
#pragma unroll
    for (int ct = 0; ct < NCT; ++ct) op[ct] = 0.f;
#pragma unroll
    for (int rt = 0; rt < 4; ++rt) {
      int jl = w * 16 + rt * 4 + q;
      float4 bs = *(const float4*)(bsum + jl * 4);
      float wf = Wfc[jl];
#pragma unroll
      for (int ct = 0; ct < NCT; ++ct) {
        float gi = acc[rt][ct][0] + bs.x;
        float gf = acc[rt][ct][1] + bs.y;
        float gg = acc[rt][ct][2] + bs.z;
        float go = acc[rt][ct][3] + bs.w;
        float ig = fast_sigmoid(gi), fg = fast_sigmoid(gf), og = fast_sigmoid(go);
        float gt = fast_tanh(gg);
        float cn = fg * cst[rt][ct] + ig * gt;
        cst[rt][ct] = cn;
        float hn = og * fast_tanh(cn);
        op[ct] += hn * wf;
        ldsH[(ct * 16 + cl) * LST + jl] = (_Float16)hn;
      }
    }
#pragma unroll
    for (int ct = 0; ct < NCT; ++ct) {
      op[ct] += __shfl_xor(op[ct], 16);
      op[ct] += __shfl_xor(op[ct], 32);
    }
    if (q == 0) {
#pragma unroll
      for (int ct = 0; ct < NCT; ++ct) obuf[w][ct * 16 + cl] = op[ct];
    }
    __syncthreads();  // BAR3: h(t) + obuf visible
    if (tid < BN) {
      int node = n0 + tid;
      if (node < NN) {
        float v = bfv;
#pragma unroll
        for (int ww = 0; ww < 8; ++ww) v += obuf[ww][tid];
        out[(size_t)node * TT + t] = v;
      }
    }
  }
}

// ---------------------------------------------------------------------------
static inline size_t alignup(size_t x) { return (x + 511) & ~(size_t)511; }

extern "C" void kernel_launch(void* const* d_in, const int* in_sizes, int n_in,
                              void* d_out, int out_size, void* d_ws, size_t ws_size,
                              hipStream_t stream) {
  const float* x_seq = (const float*)d_in[0];
  const unsigned int* e32 = (const unsigned int*)d_in[1];
  const float* W_gcn = (const float*)d_in[2];
  const float* b_gcn = (const float*)d_in[3];
  const float* W_ih = (const float*)d_in[4];
  const float* W_hh = (const float*)d_in[5];
  const float* b_ih = (const float*)d_in[6];
  const float* b_hh = (const float*)d_in[7];
  const float* W_fc = (const float*)d_in[8];
  const float* b_fc = (const float*)d_in[9];
  float* out = (float*)d_out;

  const int N = NN;
  const int E = in_sizes[1] / 2;

  char* p = (char*)d_ws;
  int* stridep = (int*)p;                    p += 512;
  int* cnt = (int*)p;                        p += alignup((size_t)N * 4);
  int* rowp = (int*)p;                       p += alignup((size_t)(N + 1) * 4);
  int* col = (int*)p;                        p += alignup((size_t)E * 4);
  float* dinv = (float*)p;                   p += alignup((size_t)N * 4);
  _Float16* xs16 = (_Float16*)p;             p += alignup((size_t)9 * N * 128 * 2);
  _Float16* agg16 = (_Float16*)p;            p += alignup((size_t)16 * 9 * N * 8 * 2);
  _Float16* wpkh = (_Float16*)p;             p += alignup((size_t)32 * 512 * 8 * 2);
  _Float16* wpkl = (_Float16*)p;             p += alignup((size_t)32 * 512 * 8 * 2);
  _Float16* wgth = (_Float16*)p;             p += alignup((size_t)16 * 128 * 8 * 2);
  _Float16* wgtl = (_Float16*)p;             p += alignup((size_t)16 * 128 * 8 * 2);
  float* bsum = (float*)p;                   p += alignup((size_t)512 * 4);

  hipMemsetAsync(cnt, 0, (size_t)N * 4, stream);

  int nchk = E < 8192 ? E : 8192;
  k_detect<<<1, 256, 0, stream>>>(e32, nchk, stridep);
  k_count<<<(E + 255) / 256, 256, 0, stream>>>(e32, E, stridep, cnt);
  k_dinv<<<(N + 255) / 256, 256, 0, stream>>>(cnt, dinv, N);
  k_scan<<<1, 1024, 0, stream>>>(cnt, rowp, N);
  hipMemsetAsync(cnt, 0, (size_t)N * 4, stream);  // reuse as fill
  k_scatter<<<(E + 255) / 256, 256, 0, stream>>>(e32, E, stridep, rowp, cnt, col);
  k_prep<<<dim3(N / 4, 9), 256, 0, stream>>>(x_seq, dinv, xs16);
  k_packw<<<512, 256, 0, stream>>>(W_ih, W_hh, b_ih, b_hh, wpkh, wpkl, bsum);
  k_packg<<<128, 128, 0, stream>>>(W_gcn, wgth, wgtl);

  k_agg<<<dim3(N / 4, 9), 256, 0, stream>>>(xs16, dinv, rowp, col, agg16);
  k_fused<<<(N + BN - 1) / BN, 512, 0, stream>>>(agg16, wgth, wgtl, b_gcn,
                                                 wpkh, wpkl, bsum, W_fc, b_fc, out);
}

// Round 12
// 1618.951 us; speedup vs baseline: 1.0458x; 1.0258x over previous
//
#include <hip/hip_runtime.h>
#include <math.h>

#define NN 50000
#define TT 9
#define FD 128
#define HD 128

using short8 = __attribute__((ext_vector_type(8))) short;
using half8  = __attribute__((ext_vector_type(8))) _Float16;
using f32x4  = __attribute__((ext_vector_type(4))) float;
using f32x2  = __attribute__((ext_vector_type(2))) float;
using half2v = __attribute__((ext_vector_type(2))) _Float16;
typedef unsigned short ushort_t;

__device__ inline float fast_sigmoid(float x) {
  x = fminf(fmaxf(x, -30.f), 30.f);
  return 1.f / (1.f + __expf(-x));
}
__device__ inline float fast_tanh(float x) {
  x = fminf(fmaxf(x, -15.f), 15.f);
  float e = __expf(2.f * x);
  return (e - 1.f) / (e + 1.f);
}

// ---------------------------------------------------------------------------
// CSR build
// ---------------------------------------------------------------------------
__global__ void k_detect(const unsigned int* __restrict__ e32, int nchk,
                         int* __restrict__ stride_out) {
  __shared__ unsigned int red[256];
  unsigned int acc = 0;
  for (int i = threadIdx.x; i < nchk; i += 256) acc |= e32[2 * i + 1];
  red[threadIdx.x] = acc;
  __syncthreads();
  for (int s = 128; s > 0; s >>= 1) {
    if ((int)threadIdx.x < s) red[threadIdx.x] |= red[threadIdx.x + s];
    __syncthreads();
  }
  if (threadIdx.x == 0) stride_out[0] = (red[0] == 0u) ? 2 : 1;
}

__global__ void k_count(const unsigned int* __restrict__ e32, int E,
                        const int* __restrict__ stridep, int* __restrict__ cnt) {
  int e = blockIdx.x * 256 + threadIdx.x;
  if (e >= E) return;
  int st = stridep[0];
  int d = (int)e32[(size_t)(E + e) * st];
  atomicAdd(&cnt[d], 1);
}

__global__ void k_dinv(const int* __restrict__ cnt, float* __restrict__ dinv, int N) {
  int n = blockIdx.x * 256 + threadIdx.x;
  if (n < N) dinv[n] = rsqrtf((float)(cnt[n] + 1));
}

__global__ void k_scan(const int* __restrict__ cnt, int* __restrict__ rowp, int N) {
  __shared__ int buf[1024];
  __shared__ int carry_s;
  if (threadIdx.x == 0) carry_s = 0;
  __syncthreads();
  for (int base = 0; base < N; base += 1024) {
    int i = base + threadIdx.x;
    int v = (i < N) ? cnt[i] : 0;
    buf[threadIdx.x] = v;
    __syncthreads();
    for (int off = 1; off < 1024; off <<= 1) {
      int t = ((int)threadIdx.x >= off) ? buf[threadIdx.x - off] : 0;
      __syncthreads();
      buf[threadIdx.x] += t;
      __syncthreads();
    }
    int incl = buf[threadIdx.x];
    int carry = carry_s;
    if (i < N) rowp[i] = carry + incl - v;
    __syncthreads();
    if (threadIdx.x == 1023) carry_s = carry + incl;
    __syncthreads();
  }
  if (threadIdx.x == 0) rowp[N] = carry_s;
}

__global__ void k_scatter(const unsigned int* __restrict__ e32, int E,
                          const int* __restrict__ stridep, const int* __restrict__ rowp,
                          int* __restrict__ fill, int* __restrict__ col) {
  int e = blockIdx.x * 256 + threadIdx.x;
  if (e >= E) return;
  int st = stridep[0];
  int s = (int)e32[(size_t)e * st];
  int d = (int)e32[(size_t)(E + e) * st];
  int pos = rowp[d] + atomicAdd(&fill[d], 1);
  col[pos] = s;
}

// ---------------------------------------------------------------------------
// k_prep: xs16[t][n][128] = fp16( x_seq[t][n][d] * dinv[n] )
// ---------------------------------------------------------------------------
__global__ __launch_bounds__(256) void k_prep(const float* __restrict__ x,
                                              const float* __restrict__ dinv,
                                              _Float16* __restrict__ xs) {
  int lane = threadIdx.x & 63;
  int n = blockIdx.x * 4 + (threadIdx.x >> 6);
  int t = blockIdx.y;
  float dn = dinv[n];
  f32x2 v = __builtin_nontemporal_load(
      (const f32x2*)(x + ((size_t)t * NN + n) * 128 + lane * 2));
  half2v r;
  r.x = (_Float16)(v.x * dn);
  r.y = (_Float16)(v.y * dn);
  *(half2v*)(xs + ((size_t)t * NN + n) * 128 + lane * 2) = r;
}

// ---------------------------------------------------------------------------
// Weight packs (k-chunked [koct][row][8], f16 hi/lo split: w = hi + lo exact
// to ~2^-22; activation operand carries the only quantization).
// ---------------------------------------------------------------------------
__global__ void k_packw(const float* __restrict__ Wih, const float* __restrict__ Whh,
                        const float* __restrict__ bih, const float* __restrict__ bhh,
                        _Float16* __restrict__ Wh_, _Float16* __restrict__ Wl_,
                        float* __restrict__ bsum) {
  int r = blockIdx.x;   // 0..511 original gate-row
  int k = threadIdx.x;  // 0..255
  int ri = (r & 127) * 4 + (r >> 7);
  float v = (k < 128) ? Wih[(size_t)r * 128 + k] : Whh[(size_t)r * 128 + (k - 128)];
  _Float16 hi = (_Float16)v;
  _Float16 lo = (_Float16)(v - (float)hi);
  size_t o = ((size_t)(k >> 3) * 512 + ri) * 8 + (k & 7);
  Wh_[o] = hi;
  Wl_[o] = lo;
  if (k == 0) bsum[ri] = bih[r] + bhh[r];
}

__global__ void k_packg(const float* __restrict__ Wg, _Float16* __restrict__ Gh_,
                        _Float16* __restrict__ Gl_) {
  int h = blockIdx.x, k = threadIdx.x;  // 128 x 128
  float v = Wg[(size_t)k * 128 + h];
  _Float16 hi = (_Float16)v;
  _Float16 lo = (_Float16)(v - (float)hi);
  size_t o = ((size_t)(k >> 3) * 128 + h) * 8 + (k & 7);
  Gh_[o] = hi;
  Gl_[o] = lo;
}

// ---------------------------------------------------------------------------
// k_agg: grid (N/4, 9) — per-t so the gather working set is 12.8MB. Wave =
// node, full 128-dim fp16 row gather, 8-edge unroll. fp32 accumulate; fp16
// output in k-chunked [koct][t][n][8] layout.
// ---------------------------------------------------------------------------
__global__ __launch_bounds__(256) void k_agg(const _Float16* __restrict__ xs,
                                             const float* __restrict__ dinv,
                                             const int* __restrict__ rowp,
                                             const int* __restrict__ col,
                                             _Float16* __restrict__ agg16) {
  __shared__ unsigned int pk[4][132];
  int lane = threadIdx.x & 63;
  int wv = threadIdx.x >> 6;
  int n = blockIdx.x * 4 + wv;
  int t = blockIdx.y;
  const _Float16* xb = xs + (size_t)t * NN * 128;
  float dn = dinv[n];
  half2v sv = *(const half2v*)(xb + (size_t)n * 128 + lane * 2);
  float ax = (float)sv.x, ay = (float)sv.y;  // self-loop (xs pre-scaled by dinv)
  int beg = rowp[n], end = rowp[n + 1];
  for (int base = beg; base < end; base += 64) {
    int m = end - base;
    if (m > 64) m = 64;
    int sl = (lane < m) ? col[base + lane] : 0;
    int j = 0;
    for (; j + 8 <= m; j += 8) {
      int s[8];
#pragma unroll
      for (int u = 0; u < 8; ++u) s[u] = __shfl(sl, j + u);
      half2v g[8];
#pragma unroll
      for (int u = 0; u < 8; ++u)
        g[u] = *(const half2v*)(xb + (size_t)s[u] * 128 + lane * 2);
#pragma unroll
      for (int u = 0; u < 8; ++u) {
        ax += (float)g[u].x;
        ay += (float)g[u].y;
      }
    }
    for (; j < m; ++j) {
      int s = __shfl(sl, j);
      half2v g = *(const half2v*)(xb + (size_t)s * 128 + lane * 2);
      ax += (float)g.x;
      ay += (float)g.y;
    }
  }
  half2v r;
  r.x = (_Float16)(ax * dn);
  r.y = (_Float16)(ay * dn);
  union { half2v h; unsigned int u; } cv;
  cv.h = r;
  pk[wv][lane] = cv.u;
  __syncthreads();
  int tid = threadIdx.x;
  if (tid < 64) {
    int g = tid & 3, c = tid >> 2;
    uint4 u4;
    u4.x = pk[g][c * 4 + 0];
    u4.y = pk[g][c * 4 + 1];
    u4.z = pk[g][c * 4 + 2];
    u4.w = pk[g][c * 4 + 3];
    int n2 = blockIdx.x * 4 + g;
    *(uint4*)(agg16 + ((size_t)(c * 9 + t) * NN + n2) * 8) = u4;
  }
}

// ---------------------------------------------------------------------------
// k_fused: GCN GEMM + full T=9 LSTM + out-projection. 512 thr x 48 nodes.
// KEY FIX (r12): the block's agg tile (12KB/t) is staged into LDS ONCE by a
// cooperative coalesced load; previously all 8 waves issued redundant global
// reads of the same tile (8x request amplification -> L2 thrash -> 1.5GB
// weight re-fetch). agg now requested once per block; L2 keeps the weights.
// ---------------------------------------------------------------------------
#define BN 48
#define NCT 3
#define LST 136  // LDS row stride in f16 elems (272B)
__global__ __launch_bounds__(512, 4) void k_fused(
    const _Float16* __restrict__ agg16, const _Float16* __restrict__ Gh_,
    const _Float16* __restrict__ Gl_, const float* __restrict__ bg,
    const _Float16* __restrict__ Wh_, const _Float16* __restrict__ Wl_,
    const float* __restrict__ bsum, const float* __restrict__ Wfc,
    const float* __restrict__ bfc, float* __restrict__ out) {
  __shared__ _Float16 ldsA[BN * LST];
  __shared__ _Float16 ldsE[BN * LST];
  __shared__ _Float16 ldsH[BN * LST];
  __shared__ float obuf[8][BN];
  int tid = threadIdx.x;
  int w = tid >> 6, lane = tid & 63, q = lane >> 4, cl = lane & 15;
  int n0 = blockIdx.x * BN;
  float cst[4][NCT] = {};
  float bfv = bfc[0];
#pragma unroll 1
  for (int t = 0; t < TT; ++t) {
    // ---- Stage agg tile into LDS (once per block; coalesced 256B runs) ----
    {
      const half8 zz8 = {0, 0, 0, 0, 0, 0, 0, 0};
#pragma unroll
      for (int pass = 0; pass < 2; ++pass) {
        int s = tid + pass * 512;
        if (s < 768) {
          int chunk = s / 48, nl = s - chunk * 48;
          int node = n0 + nl;
          half8 v = zz8;
          if (node < NN)
            v = *(const half8*)(agg16 + ((size_t)(chunk * 9 + t) * NN + node) * 8);
          *(half8*)(ldsA + nl * LST + chunk * 8) = v;
        }
      }
    }
    __syncthreads();  // BAR0: ldsA(t) ready
    // ---- Phase E: emb^T = Wgt @ agg^T (A split-f16, B f16: 2 MFMA) ----
    {
      f32x4 acce[NCT] = {};
#pragma unroll 2
      for (int ks = 0; ks < 4; ++ks) {
        int chunk = ks * 4 + q;
        size_t wo = ((size_t)chunk * 128 + w * 16 + cl) * 8;
        half8 gah = *(const half8*)(Gh_ + wo);
        half8 gal = *(const half8*)(Gl_ + wo);
#pragma unroll
        for (int ct = 0; ct < NCT; ++ct) {
          half8 b = *(const half8*)(ldsA + (ct * 16 + cl) * LST + chunk * 8);
          acce[ct] = __builtin_amdgcn_mfma_f32_16x16x32_f16(gah, b, acce[ct], 0, 0, 0);
          acce[ct] = __builtin_amdgcn_mfma_f32_16x16x32_f16(gal, b, acce[ct], 0, 0, 0);
        }
      }
#pragma unroll
      for (int ct = 0; ct < NCT; ++ct) {
#pragma unroll
        for (int j = 0; j < 4; ++j) {
          int hid = w * 16 + q * 4 + j;
          float v = acce[ct][j] + bg[hid];
          v = v > 0.f ? v : 0.f;
          ldsE[(ct * 16 + cl) * LST + hid] = (_Float16)v;
        }
      }
    }
    __syncthreads();  // BAR1: ldsE(t) ready; all ldsA reads done
    // ---- Phase G: gates^T = Wpk @ [emb|h]^T (A split-f16, B f16) ----
    f32x4 acc[4][NCT] = {};
    int ksmax = (t == 0) ? 4 : 8;
#pragma unroll 2
    for (int ks = 0; ks < ksmax; ++ks) {
      int chunk = ks * 4 + q;
      const _Float16* Bp = (ks < 4) ? ldsE : ldsH;
      int kk = (ks & 3) * 32 + q * 8;
      half8 bb[NCT];
#pragma unroll
      for (int ct = 0; ct < NCT; ++ct)
        bb[ct] = *(const half8*)(Bp + (ct * 16 + cl) * LST + kk);
#pragma unroll
      for (int rt = 0; rt < 4; ++rt) {
        size_t ao = ((size_t)chunk * 512 + w * 64 + rt * 16 + cl) * 8;
        half8 ah = *(const half8*)(Wh_ + ao);
        half8 al = *(const half8*)(Wl_ + ao);
#pragma unroll
        for (int ct = 0; ct < NCT; ++ct) {
          acc[rt][ct] = __builtin_amdgcn_mfma_f32_16x16x32_f16(ah, bb[ct], acc[rt][ct], 0, 0, 0);
          acc[rt][ct] = __builtin_amdgcn_mfma_f32_16x16x32_f16(al, bb[ct], acc[rt][ct], 0, 0, 0);
        }
      }
    }
    __syncthreads();  // BAR2: all ldsE/ldsH reads done before h(t) writes
    // ---- Epilogue ----
    float op[NCT];
#pragma unroll
    for (int ct = 0; ct < NCT; ++ct) op[ct] = 0.f;
#pragma unroll
    for (int rt = 0; rt < 4; ++rt) {
      int jl = w * 16 + rt * 4 + q;
      float4 bs = *(const float4*)(bsum + jl * 4);
      float wf = Wfc[jl];
#pragma unroll
      for (int ct = 0; ct < NCT; ++ct) {
        float gi = acc[rt][ct][0] + bs.x;
        float gf = acc[rt][ct][1] + bs.y;
        float gg = acc[rt][ct][2] + bs.z;
        float go = acc[rt][ct][3] + bs.w;
        float ig = fast_sigmoid(gi), fg = fast_sigmoid(gf), og = fast_sigmoid(go);
        float gt = fast_tanh(gg);
        float cn = fg * cst[rt][ct] + ig * gt;
        cst[rt][ct] = cn;
        float hn = og * fast_tanh(cn);
        op[ct] += hn * wf;
        ldsH[(ct * 16 + cl) * LST + jl] = (_Float16)hn;
      }
    }
#pragma unroll
    for (int ct = 0; ct < NCT; ++ct) {
      op[ct] += __shfl_xor(op[ct], 16);
      op[ct] += __shfl_xor(op[ct], 32);
    }
    if (q == 0) {
#pragma unroll
      for (int ct = 0; ct < NCT; ++ct) obuf[w][ct * 16 + cl] = op[ct];
    }
    __syncthreads();  // BAR3: h(t) + obuf visible
    if (tid < BN) {
      int node = n0 + tid;
      if (node < NN) {
        float v = bfv;
#pragma unroll
        for (int ww = 0; ww < 8; ++ww) v += obuf[ww][tid];
        out[(size_t)node * TT + t] = v;
      }
    }
  }
}

// ---------------------------------------------------------------------------
static inline size_t alignup(size_t x) { return (x + 511) & ~(size_t)511; }

extern "C" void kernel_launch(void* const* d_in, const int* in_sizes, int n_in,
                              void* d_out, int out_size, void* d_ws, size_t ws_size,
                              hipStream_t stream) {
  const float* x_seq = (const float*)d_in[0];
  const unsigned int* e32 = (const unsigned int*)d_in[1];
  const float* W_gcn = (const float*)d_in[2];
  const float* b_gcn = (const float*)d_in[3];
  const float* W_ih = (const float*)d_in[4];
  const float* W_hh = (const float*)d_in[5];
  const float* b_ih = (const float*)d_in[6];
  const float* b_hh = (const float*)d_in[7];
  const float* W_fc = (const float*)d_in[8];
  const float* b_fc = (const float*)d_in[9];
  float* out = (float*)d_out;

  const int N = NN;
  const int E = in_sizes[1] / 2;

  char* p = (char*)d_ws;
  int* stridep = (int*)p;                    p += 512;
  int* cnt = (int*)p;                        p += alignup((size_t)N * 4);
  int* rowp = (int*)p;                       p += alignup((size_t)(N + 1) * 4);
  int* col = (int*)p;                        p += alignup((size_t)E * 4);
  float* dinv = (float*)p;                   p += alignup((size_t)N * 4);
  _Float16* xs16 = (_Float16*)p;             p += alignup((size_t)9 * N * 128 * 2);
  _Float16* agg16 = (_Float16*)p;            p += alignup((size_t)16 * 9 * N * 8 * 2);
  _Float16* wpkh = (_Float16*)p;             p += alignup((size_t)32 * 512 * 8 * 2);
  _Float16* wpkl = (_Float16*)p;             p += alignup((size_t)32 * 512 * 8 * 2);
  _Float16* wgth = (_Float16*)p;             p += alignup((size_t)16 * 128 * 8 * 2);
  _Float16* wgtl = (_Float16*)p;             p += alignup((size_t)16 * 128 * 8 * 2);
  float* bsum = (float*)p;                   p += alignup((size_t)512 * 4);

  hipMemsetAsync(cnt, 0, (size_t)N * 4, stream);

  int nchk = E < 8192 ? E : 8192;
  k_detect<<<1, 256, 0, stream>>>(e32, nchk, stridep);
  k_count<<<(E + 255) / 256, 256, 0, stream>>>(e32, E, stridep, cnt);
  k_dinv<<<(N + 255) / 256, 256, 0, stream>>>(cnt, dinv, N);
  k_scan<<<1, 1024, 0, stream>>>(cnt, rowp, N);
  hipMemsetAsync(cnt, 0, (size_t)N * 4, stream);  // reuse as fill
  k_scatter<<<(E + 255) / 256, 256, 0, stream>>>(e32, E, stridep, rowp, cnt, col);
  k_prep<<<dim3(N / 4, 9), 256, 0, stream>>>(x_seq, dinv, xs16);
  k_packw<<<512, 256, 0, stream>>>(W_ih, W_hh, b_ih, b_hh, wpkh, wpkl, bsum);
  k_packg<<<128, 128, 0, stream>>>(W_gcn, wgth, wgtl);

  k_agg<<<dim3(N / 4, 9), 256, 0, stream>>>(xs16, dinv, rowp, col, agg16);
  k_fused<<<(N + BN - 1) / BN, 512, 0, stream>>>(agg16, wgth, wgtl, b_gcn,
                                                 wpkh, wpkl, bsum, W_fc, b_fc, out);
}

// Round 13
// 1598.782 us; speedup vs baseline: 1.0590x; 1.0126x over previous
//
#include <hip/hip_runtime.h>
#include <math.h>

#define NN 50000
#define TT 9
#define FD 128
#define HD 128

using short8 = __attribute__((ext_vector_type(8))) short;
using half8  = __attribute__((ext_vector_type(8))) _Float16;
using f32x4  = __attribute__((ext_vector_type(4))) float;
using f32x2  = __attribute__((ext_vector_type(2))) float;
using half2v = __attribute__((ext_vector_type(2))) _Float16;
typedef unsigned short ushort_t;

__device__ inline float fast_sigmoid(float x) {
  x = fminf(fmaxf(x, -30.f), 30.f);
  return 1.f / (1.f + __expf(-x));
}
__device__ inline float fast_tanh(float x) {
  x = fminf(fmaxf(x, -15.f), 15.f);
  float e = __expf(2.f * x);
  return (e - 1.f) / (e + 1.f);
}

// ---------------------------------------------------------------------------
// CSR build
// ---------------------------------------------------------------------------
__global__ void k_detect(const unsigned int* __restrict__ e32, int nchk,
                         int* __restrict__ stride_out) {
  __shared__ unsigned int red[256];
  unsigned int acc = 0;
  for (int i = threadIdx.x; i < nchk; i += 256) acc |= e32[2 * i + 1];
  red[threadIdx.x] = acc;
  __syncthreads();
  for (int s = 128; s > 0; s >>= 1) {
    if ((int)threadIdx.x < s) red[threadIdx.x] |= red[threadIdx.x + s];
    __syncthreads();
  }
  if (threadIdx.x == 0) stride_out[0] = (red[0] == 0u) ? 2 : 1;
}

__global__ void k_count(const unsigned int* __restrict__ e32, int E,
                        const int* __restrict__ stridep, int* __restrict__ cnt) {
  int e = blockIdx.x * 256 + threadIdx.x;
  if (e >= E) return;
  int st = stridep[0];
  int d = (int)e32[(size_t)(E + e) * st];
  atomicAdd(&cnt[d], 1);
}

__global__ void k_dinv(const int* __restrict__ cnt, float* __restrict__ dinv, int N) {
  int n = blockIdx.x * 256 + threadIdx.x;
  if (n < N) dinv[n] = rsqrtf((float)(cnt[n] + 1));
}

__global__ void k_scan(const int* __restrict__ cnt, int* __restrict__ rowp, int N) {
  __shared__ int buf[1024];
  __shared__ int carry_s;
  if (threadIdx.x == 0) carry_s = 0;
  __syncthreads();
  for (int base = 0; base < N; base += 1024) {
    int i = base + threadIdx.x;
    int v = (i < N) ? cnt[i] : 0;
    buf[threadIdx.x] = v;
    __syncthreads();
    for (int off = 1; off < 1024; off <<= 1) {
      int t = ((int)threadIdx.x >= off) ? buf[threadIdx.x - off] : 0;
      __syncthreads();
      buf[threadIdx.x] += t;
      __syncthreads();
    }
    int incl = buf[threadIdx.x];
    int carry = carry_s;
    if (i < N) rowp[i] = carry + incl - v;
    __syncthreads();
    if (threadIdx.x == 1023) carry_s = carry + incl;
    __syncthreads();
  }
  if (threadIdx.x == 0) rowp[N] = carry_s;
}

__global__ void k_scatter(const unsigned int* __restrict__ e32, int E,
                          const int* __restrict__ stridep, const int* __restrict__ rowp,
                          int* __restrict__ fill, int* __restrict__ col) {
  int e = blockIdx.x * 256 + threadIdx.x;
  if (e >= E) return;
  int st = stridep[0];
  int s = (int)e32[(size_t)e * st];
  int d = (int)e32[(size_t)(E + e) * st];
  int pos = rowp[d] + atomicAdd(&fill[d], 1);
  col[pos] = s;
}

// ---------------------------------------------------------------------------
// k_prep: xs16[t][n][128] = fp16( x_seq[t][n][d] * dinv[n] )
// ---------------------------------------------------------------------------
__global__ __launch_bounds__(256) void k_prep(const float* __restrict__ x,
                                              const float* __restrict__ dinv,
                                              _Float16* __restrict__ xs) {
  int lane = threadIdx.x & 63;
  int n = blockIdx.x * 4 + (threadIdx.x >> 6);
  int t = blockIdx.y;
  float dn = dinv[n];
  f32x2 v = __builtin_nontemporal_load(
      (const f32x2*)(x + ((size_t)t * NN + n) * 128 + lane * 2));
  half2v r;
  r.x = (_Float16)(v.x * dn);
  r.y = (_Float16)(v.y * dn);
  *(half2v*)(xs + ((size_t)t * NN + n) * 128 + lane * 2) = r;
}

// ---------------------------------------------------------------------------
// Weight packs (k-chunked [koct][row][8], f16 hi/lo split: w = hi + lo exact
// to ~2^-22; activation operand carries the only quantization).
// ---------------------------------------------------------------------------
__global__ void k_packw(const float* __restrict__ Wih, const float* __restrict__ Whh,
                        const float* __restrict__ bih, const float* __restrict__ bhh,
                        _Float16* __restrict__ Wh_, _Float16* __restrict__ Wl_,
                        float* __restrict__ bsum) {
  int r = blockIdx.x;   // 0..511 original gate-row
  int k = threadIdx.x;  // 0..255
  int ri = (r & 127) * 4 + (r >> 7);
  float v = (k < 128) ? Wih[(size_t)r * 128 + k] : Whh[(size_t)r * 128 + (k - 128)];
  _Float16 hi = (_Float16)v;
  _Float16 lo = (_Float16)(v - (float)hi);
  size_t o = ((size_t)(k >> 3) * 512 + ri) * 8 + (k & 7);
  Wh_[o] = hi;
  Wl_[o] = lo;
  if (k == 0) bsum[ri] = bih[r] + bhh[r];
}

__global__ void k_packg(const float* __restrict__ Wg, _Float16* __restrict__ Gh_,
                        _Float16* __restrict__ Gl_) {
  int h = blockIdx.x, k = threadIdx.x;  // 128 x 128
  float v = Wg[(size_t)k * 128 + h];
  _Float16 hi = (_Float16)v;
  _Float16 lo = (_Float16)(v - (float)hi);
  size_t o = ((size_t)(k >> 3) * 128 + h) * 8 + (k & 7);
  Gh_[o] = hi;
  Gl_[o] = lo;
}

// ---------------------------------------------------------------------------
// k_agg: grid (N/4, 9) — per-t so the gather working set is 12.8MB. Wave =
// node, full 128-dim fp16 row gather, 8-edge unroll. fp32 accumulate; fp16
// output in k-chunked [koct][t][n][8] layout.
// ---------------------------------------------------------------------------
__global__ __launch_bounds__(256) void k_agg(const _Float16* __restrict__ xs,
                                             const float* __restrict__ dinv,
                                             const int* __restrict__ rowp,
                                             const int* __restrict__ col,
                                             _Float16* __restrict__ agg16) {
  __shared__ unsigned int pk[4][132];
  int lane = threadIdx.x & 63;
  int wv = threadIdx.x >> 6;
  int n = blockIdx.x * 4 + wv;
  int t = blockIdx.y;
  const _Float16* xb = xs + (size_t)t * NN * 128;
  float dn = dinv[n];
  half2v sv = *(const half2v*)(xb + (size_t)n * 128 + lane * 2);
  float ax = (float)sv.x, ay = (float)sv.y;  // self-loop (xs pre-scaled by dinv)
  int beg = rowp[n], end = rowp[n + 1];
  for (int base = beg; base < end; base += 64) {
    int m = end - base;
    if (m > 64) m = 64;
    int sl = (lane < m) ? col[base + lane] : 0;
    int j = 0;
    for (; j + 8 <= m; j += 8) {
      int s[8];
#pragma unroll
      for (int u = 0; u < 8; ++u) s[u] = __shfl(sl, j + u);
      half2v g[8];
#pragma unroll
      for (int u = 0; u < 8; ++u)
        g[u] = *(const half2v*)(xb + (size_t)s[u] * 128 + lane * 2);
#pragma unroll
      for (int u = 0; u < 8; ++u) {
        ax += (float)g[u].x;
        ay += (float)g[u].y;
      }
    }
    for (; j < m; ++j) {
      int s = __shfl(sl, j);
      half2v g = *(const half2v*)(xb + (size_t)s * 128 + lane * 2);
      ax += (float)g.x;
      ay += (float)g.y;
    }
  }
  half2v r;
  r.x = (_Float16)(ax * dn);
  r.y = (_Float16)(ay * dn);
  union { half2v h; unsigned int u; } cv;
  cv.h = r;
  pk[wv][lane] = cv.u;
  __syncthreads();
  int tid = threadIdx.x;
  if (tid < 64) {
    int g = tid & 3, c = tid >> 2;
    uint4 u4;
    u4.x = pk[g][c * 4 + 0];
    u4.y = pk[g][c * 4 + 1];
    u4.z = pk[g][c * 4 + 2];
    u4.w = pk[g][c * 4 + 3];
    int n2 = blockIdx.x * 4 + g;
    *(uint4*)(agg16 + ((size_t)(c * 9 + t) * NN + n2) * 8) = u4;
  }
}

// ---------------------------------------------------------------------------
// k_fused: GCN GEMM + full T=9 LSTM + out-projection. 512 thr x 48 nodes.
// r13: agg tile staged via ASYNC global_load_lds into a double-buffered
// LINEAR ldsA (prefetch t+1 issued at top of t, flies under Phase E; BAR1's
// implicit vmcnt(0) drain guarantees completion). BAR0 eliminated (3
// barriers/t). Zero extra VGPRs -> keeps VGPR=64 / 2 blocks/CU.
// ---------------------------------------------------------------------------
#define BN 48
#define NCT 3
#define LST 136  // LDS row stride (f16) for E/H planes
__global__ __launch_bounds__(512, 4) void k_fused(
    const _Float16* __restrict__ agg16, const _Float16* __restrict__ Gh_,
    const _Float16* __restrict__ Gl_, const float* __restrict__ bg,
    const _Float16* __restrict__ Wh_, const _Float16* __restrict__ Wl_,
    const float* __restrict__ bsum, const float* __restrict__ Wfc,
    const float* __restrict__ bfc, float* __restrict__ out) {
  __shared__ _Float16 ldsA[2][16 * BN * 8];  // linear: unit s=(chunk*48+nl) -> s*8
  __shared__ _Float16 ldsE[BN * LST];
  __shared__ _Float16 ldsH[BN * LST];
  __shared__ float obuf[8][BN];
  int tid = threadIdx.x;
  int w = tid >> 6, lane = tid & 63, q = lane >> 4, cl = lane & 15;
  int n0 = blockIdx.x * BN;
  float cst[4][NCT] = {};
  float bfv = bfc[0];
  // staging unit mapping: 768 units of 16B; unit s -> chunk=s/48, nl=s%48
  int cA = tid / BN, nA = tid - cA * BN;
  int nodeA = n0 + nA; if (nodeA >= NN) nodeA = NN - 1;  // clamp: pad cols unused
  int sB = tid + 512;
  int cB = sB / BN, nB = sB - cB * BN;
  int nodeB = n0 + nB; if (nodeB >= NN) nodeB = NN - 1;

  // prologue: stage t=0 into buffer 0 (async; drained by the syncthreads)
  __builtin_amdgcn_global_load_lds(
      (const __attribute__((address_space(1))) void*)(agg16 + ((size_t)(cA * 9 + 0) * NN + nodeA) * 8),
      (__attribute__((address_space(3))) void*)(&ldsA[0][tid * 8]), 16, 0, 0);
  if (tid < 256)
    __builtin_amdgcn_global_load_lds(
        (const __attribute__((address_space(1))) void*)(agg16 + ((size_t)(cB * 9 + 0) * NN + nodeB) * 8),
        (__attribute__((address_space(3))) void*)(&ldsA[0][sB * 8]), 16, 0, 0);
  __syncthreads();

#pragma unroll 1
  for (int t = 0; t < TT; ++t) {
    const _Float16* Ab = ldsA[t & 1];
    // ---- issue async prefetch of agg tile (t+1) into the other buffer ----
    if (t + 1 < TT) {
      int bs = (t + 1) & 1;
      __builtin_amdgcn_global_load_lds(
          (const __attribute__((address_space(1))) void*)(agg16 + ((size_t)(cA * 9 + (t + 1)) * NN + nodeA) * 8),
          (__attribute__((address_space(3))) void*)(&ldsA[bs][tid * 8]), 16, 0, 0);
      if (tid < 256)
        __builtin_amdgcn_global_load_lds(
            (const __attribute__((address_space(1))) void*)(agg16 + ((size_t)(cB * 9 + (t + 1)) * NN + nodeB) * 8),
            (__attribute__((address_space(3))) void*)(&ldsA[bs][sB * 8]), 16, 0, 0);
    }
    // ---- Phase E: emb^T = Wgt @ agg^T (A split-f16, B f16: 2 MFMA) ----
    {
      f32x4 acce[NCT] = {};
#pragma unroll 2
      for (int ks = 0; ks < 4; ++ks) {
        int chunk = ks * 4 + q;
        size_t wo = ((size_t)chunk * 128 + w * 16 + cl) * 8;
        half8 gah = *(const half8*)(Gh_ + wo);
        half8 gal = *(const half8*)(Gl_ + wo);
#pragma unroll
        for (int ct = 0; ct < NCT; ++ct) {
          half8 b = *(const half8*)(Ab + (chunk * BN + ct * 16 + cl) * 8);
          acce[ct] = __builtin_amdgcn_mfma_f32_16x16x32_f16(gah, b, acce[ct], 0, 0, 0);
          acce[ct] = __builtin_amdgcn_mfma_f32_16x16x32_f16(gal, b, acce[ct], 0, 0, 0);
        }
      }
#pragma unroll
      for (int ct = 0; ct < NCT; ++ct) {
#pragma unroll
        for (int j = 0; j < 4; ++j) {
          int hid = w * 16 + q * 4 + j;
          float v = acce[ct][j] + bg[hid];
          v = v > 0.f ? v : 0.f;
          ldsE[(ct * 16 + cl) * LST + hid] = (_Float16)v;
        }
      }
    }
    __syncthreads();  // BAR1: ldsE ready; prefetch drained; ldsA reads done
    // ---- Phase G: gates^T = Wpk @ [emb|h]^T (A split-f16, B f16) ----
    f32x4 acc[4][NCT] = {};
    int ksmax = (t == 0) ? 4 : 8;
#pragma unroll 2
    for (int ks = 0; ks < ksmax; ++ks) {
      int chunk = ks * 4 + q;
      const _Float16* Bp = (ks < 4) ? ldsE : ldsH;
      int kk = (ks & 3) * 32 + q * 8;
      half8 bb[NCT];
#pragma unroll
      for (int ct = 0; ct < NCT; ++ct)
        bb[ct] = *(const half8*)(Bp + (ct * 16 + cl) * LST + kk);
#pragma unroll
      for (int rt = 0; rt < 4; ++rt) {
        size_t ao = ((size_t)chunk * 512 + w * 64 + rt * 16 + cl) * 8;
        half8 ah = *(const half8*)(Wh_ + ao);
        half8 al = *(const half8*)(Wl_ + ao);
#pragma unroll
        for (int ct = 0; ct < NCT; ++ct) {
          acc[rt][ct] = __builtin_amdgcn_mfma_f32_16x16x32_f16(ah, bb[ct], acc[rt][ct], 0, 0, 0);
          acc[rt][ct] = __builtin_amdgcn_mfma_f32_16x16x32_f16(al, bb[ct], acc[rt][ct], 0, 0, 0);
        }
      }
    }
    __syncthreads();  // BAR2: all ldsE/ldsH reads done before h(t) writes
    // ---- Epilogue ----
    float op[NCT];
#pragma unroll
    for (int ct = 0; ct < NCT; ++ct) op[ct] = 0.f;
#pragma unroll
    for (int rt = 0; rt < 4; ++rt) {
      int jl = w * 16 + rt * 4 + q;
      float4 bs = *(const float4*)(bsum + jl * 4);
      float wf = Wfc[jl];
#pragma unroll
      for (int ct = 0; ct < NCT; ++ct) {
        float gi = acc[rt][ct][0] + bs.x;
        float gf = acc[rt][ct][1] + bs.y;
        float gg = acc[rt][ct][2] + bs.z;
        float go = acc[rt][ct][3] + bs.w;
        float ig = fast_sigmoid(gi), fg = fast_sigmoid(gf), og = fast_sigmoid(go);
        float gt = fast_tanh(gg);
        float cn = fg * cst[rt][ct] + ig * gt;
        cst[rt][ct] = cn;
        float hn = og * fast_tanh(cn);
        op[ct] += hn * wf;
        ldsH[(ct * 16 + cl) * LST + jl] = (_Float16)hn;
      }
    }
#pragma unroll
    for (int ct = 0; ct < NCT; ++ct) {
      op[ct] += __shfl_xor(op[ct], 16);
      op[ct] += __shfl_xor(op[ct], 32);
    }
    if (q == 0) {
#pragma unroll
      for (int ct = 0; ct < NCT; ++ct) obuf[w][ct * 16 + cl] = op[ct];
    }
    __syncthreads();  // BAR3: h(t) + obuf visible
    if (tid < BN) {
      int node = n0 + tid;
      if (node < NN) {
        float v = bfv;
#pragma unroll
        for (int ww = 0; ww < 8; ++ww) v += obuf[ww][tid];
        out[(size_t)node * TT + t] = v;
      }
    }
  }
}

// ---------------------------------------------------------------------------
static inline size_t alignup(size_t x) { return (x + 511) & ~(size_t)511; }

extern "C" void kernel_launch(void* const* d_in, const int* in_sizes, int n_in,
                              void* d_out, int out_size, void* d_ws, size_t ws_size,
                              hipStream_t stream) {
  const float* x_seq = (const float*)d_in[0];
  const unsigned int* e32 = (const unsigned int*)d_in[1];
  const float* W_gcn = (const float*)d_in[2];
  const float* b_gcn = (const float*)d_in[3];
  const float* W_ih = (const float*)d_in[4];
  const float* W_hh = (const float*)d_in[5];
  const float* b_ih = (const float*)d_in[6];
  const float* b_hh = (const float*)d_in[7];
  const float* W_fc = (const float*)d_in[8];
  const float* b_fc = (const float*)d_in[9];
  float* out = (float*)d_out;

  const int N = NN;
  const int E = in_sizes[1] / 2;

  char* p = (char*)d_ws;
  int* stridep = (int*)p;                    p += 512;
  int* cnt = (int*)p;                        p += alignup((size_t)N * 4);
  int* rowp = (int*)p;                       p += alignup((size_t)(N + 1) * 4);
  int* col = (int*)p;                        p += alignup((size_t)E * 4);
  float* dinv = (float*)p;                   p += alignup((size_t)N * 4);
  _Float16* xs16 = (_Float16*)p;             p += alignup((size_t)9 * N * 128 * 2);
  _Float16* agg16 = (_Float16*)p;            p += alignup((size_t)16 * 9 * N * 8 * 2);
  _Float16* wpkh = (_Float16*)p;             p += alignup((size_t)32 * 512 * 8 * 2);
  _Float16* wpkl = (_Float16*)p;             p += alignup((size_t)32 * 512 * 8 * 2);
  _Float16* wgth = (_Float16*)p;             p += alignup((size_t)16 * 128 * 8 * 2);
  _Float16* wgtl = (_Float16*)p;             p += alignup((size_t)16 * 128 * 8 * 2);
  float* bsum = (float*)p;                   p += alignup((size_t)512 * 4);

  hipMemsetAsync(cnt, 0, (size_t)N * 4, stream);

  int nchk = E < 8192 ? E : 8192;
  k_detect<<<1, 256, 0, stream>>>(e32, nchk, stridep);
  k_count<<<(E + 255) / 256, 256, 0, stream>>>(e32, E, stridep, cnt);
  k_dinv<<<(N + 255) / 256, 256, 0, stream>>>(cnt, dinv, N);
  k_scan<<<1, 1024, 0, stream>>>(cnt, rowp, N);
  hipMemsetAsync(cnt, 0, (size_t)N * 4, stream);  // reuse as fill
  k_scatter<<<(E + 255) / 256, 256, 0, stream>>>(e32, E, stridep, rowp, cnt, col);
  k_prep<<<dim3(N / 4, 9), 256, 0, stream>>>(x_seq, dinv, xs16);
  k_packw<<<512, 256, 0, stream>>>(W_ih, W_hh, b_ih, b_hh, wpkh, wpkl, bsum);
  k_packg<<<128, 128, 0, stream>>>(W_gcn, wgth, wgtl);

  k_agg<<<dim3(N / 4, 9), 256, 0, stream>>>(xs16, dinv, rowp, col, agg16);
  k_fused<<<(N + BN - 1) / BN, 512, 0, stream>>>(agg16, wgth, wgtl, b_gcn,
                                                 wpkh, wpkl, bsum, W_fc, b_fc, out);
}